// Round 3
// baseline (911.380 us; speedup 1.0000x reference)
//
#include <hip/hip_runtime.h>
#include <math.h>

#define N_ATOMS 4096
#define L_WORDS 65536
#define DD 10
#define HALO 11

#define CONV_BLOCKS 256
#define CONV_BLOCK 256
#define GNN_BLOCKS 512            // 128 row-groups x 4 column quarters
#define RPW 8                     // rows per wave
#define RPB 32                    // rows per block (4 waves)
#define QCOLS 1024                // columns per quarter
#define TOTAL_BLOCKS (CONV_BLOCKS + GNN_BLOCKS)   // 768 = 3 blocks/CU

// ---------------------------------------------------------------------------
// Grid barrier: 8 single-use slots in ws, zeroed by hipMemsetAsync each run.
// Release side: __threadfence() (L2 writeback) + agent-scope fetch_add.
// Acquire side: agent-scope spin + __threadfence() (invalidate stale lines).
// Only tid 0 spins; slots never reused within a run -> no reset race.
// ---------------------------------------------------------------------------
__device__ __forceinline__ void gridbar(unsigned int* __restrict__ bar, int k)
{
    __syncthreads();                       // all waves' stores drained (vmcnt0)
    if (threadIdx.x == 0) {
        __threadfence();                   // writeback this XCD's dirty L2
        __hip_atomic_fetch_add(bar + k, 1u, __ATOMIC_ACQ_REL,
                               __HIP_MEMORY_SCOPE_AGENT);
        while (__hip_atomic_load(bar + k, __ATOMIC_ACQUIRE,
                                 __HIP_MEMORY_SCOPE_AGENT) < (unsigned)TOTAL_BLOCKS)
            __builtin_amdgcn_s_sleep(8);
        __threadfence();                   // invalidate before re-reading data
    }
    __syncthreads();
}

// ---------------------------------------------------------------------------
// conv stage: one CNN layer over this block's 256 words (unchanged math)
// ---------------------------------------------------------------------------
__device__ __forceinline__ void conv_stage(
    float* sh, const int tid, const int bx,
    const float* __restrict__ tin, const int* __restrict__ words,
    const float* __restrict__ embed_word, const float* __restrict__ w,
    const float* __restrict__ bptr, float* __restrict__ tout)
{
    const int l0 = bx * CONV_BLOCK;
    for (int idx = tid; idx < (CONV_BLOCK + 2 * HALO) * DD; idx += CONV_BLOCK) {
        int rr = idx / DD, d = idx - rr * DD;
        int gr = l0 - HALO + rr;
        float v = 0.f;
        if (gr >= 0 && gr < L_WORDS) {
            if (tin) v = tin[(size_t)gr * DD + d];
            else     v = embed_word[(size_t)words[gr] * DD + d];
        }
        sh[rr * 11 + d] = v;
    }
    __syncthreads();

    const float bias = *bptr;
    float acc[DD];
    #pragma unroll
    for (int d = 0; d < DD; ++d) acc[d] = bias;
    for (int i = 0; i < 23; ++i) {
        float row[DD];
        const float* sr = &sh[(tid + i) * 11];
        #pragma unroll
        for (int c = 0; c < DD; ++c) row[c] = sr[c];
        #pragma unroll
        for (int d = 0; d < DD; ++d) {
            #pragma unroll
            for (int c = 0; c < DD; ++c)
                acc[d] += row[c] * w[i * 23 + (c - d + 11)];
        }
    }
    const int l = l0 + tid;
    #pragma unroll
    for (int d = 0; d < DD; ++d)
        tout[(size_t)l * DD + d] = fmaxf(acc[d], 0.f);
    __syncthreads();                 // sh reused next stage
}

// ---------------------------------------------------------------------------
// gnn stage: A@hs partial over a 1024-column quarter (unchanged math, SoA)
// ---------------------------------------------------------------------------
__device__ __forceinline__ void gnn_stage(
    float* sh, const int tid, const int b,
    const float* __restrict__ A, const float* __restrict__ hs,
    float* __restrict__ part)
{
    const int wave = tid >> 6, lane = tid & 63;
    const int q = b & 3, rg = b >> 2;

    // stage hs quarter: coalesced plane copy
    const float4* h4 = (const float4*)hs;
    float4* shw = (float4*)sh;
    #pragma unroll
    for (int d = 0; d < DD; ++d)
        shw[d * 256 + tid] = h4[d * (N_ATOMS / 4) + q * 256 + tid];
    __syncthreads();

    const int r0 = rg * RPB + wave * RPW;
    const float4* A4 = (const float4*)(A + (size_t)r0 * N_ATOMS) + q * (QCOLS / 4);
    const float4* sh4 = (const float4*)sh;

    float acc[RPW][DD];
    #pragma unroll
    for (int r = 0; r < RPW; ++r)
        #pragma unroll
        for (int d = 0; d < DD; ++d) acc[r][d] = 0.f;

    #pragma unroll 1
    for (int it = 0; it < 4; ++it) {
        const int cb = it * 64 + lane;
        float4 a[RPW];
        #pragma unroll
        for (int r = 0; r < RPW; ++r) a[r] = A4[r * (N_ATOMS / 4) + cb];
        #pragma unroll
        for (int d = 0; d < DD; ++d) {
            float4 h = sh4[d * 256 + cb];
            #pragma unroll
            for (int r = 0; r < RPW; ++r) {
                acc[r][d] += a[r].x * h.x;
                acc[r][d] += a[r].y * h.y;
                acc[r][d] += a[r].z * h.z;
                acc[r][d] += a[r].w * h.w;
            }
        }
    }

    #pragma unroll
    for (int m = 1; m <= 4; m <<= 1) {
        #pragma unroll
        for (int r = 0; r < RPW; ++r)
            #pragma unroll
            for (int d = 0; d < DD; ++d)
                acc[r][d] += __shfl_xor(acc[r][d], m, 64);
    }
    __syncthreads();

    if ((lane & 7) == 0) {
        const int g = lane >> 3;
        float* dst = &sh[(wave * 8 + g) * 80];
        #pragma unroll
        for (int r = 0; r < RPW; ++r)
            #pragma unroll
            for (int d = 0; d < DD; ++d) dst[r * DD + d] = acc[r][d];
    }
    __syncthreads();

    float* pdst = part + (size_t)q * DD * N_ATOMS + (size_t)rg * RPB;
    for (int o = tid; o < RPB * DD; o += 256) {
        const int d = o >> 5, rr = o & 31;
        const int w8 = rr >> 3, r = rr & 7;
        float v = 0.f;
        #pragma unroll
        for (int g = 0; g < 8; ++g) v += sh[(w8 * 8 + g) * 80 + r * DD + d];
        pdst[d * N_ATOMS + rr] = v;
    }
    __syncthreads();                 // sh reused next stage
}

// ---------------------------------------------------------------------------
// embed stage: xs0 planes + hs0 = relu(W0 xs0 + b0)   (16 blocks x 256 atoms)
// ---------------------------------------------------------------------------
__device__ __forceinline__ void embed_stage(
    const int gb, const int tid,
    const int* __restrict__ fp, const float* __restrict__ embed_fp,
    const float* __restrict__ Wg, const float* __restrict__ bg,
    float* __restrict__ xs, float* __restrict__ hs)
{
    const int n = gb * 256 + tid;
    float x[DD];
    const float* e = embed_fp + (size_t)fp[n] * DD;
    #pragma unroll
    for (int d = 0; d < DD; ++d) x[d] = e[d];
    #pragma unroll
    for (int d = 0; d < DD; ++d) xs[d * N_ATOMS + n] = x[d];
    #pragma unroll
    for (int d = 0; d < DD; ++d) {
        float v = bg[d];
        #pragma unroll
        for (int k = 0; k < DD; ++k) v += Wg[d * DD + k] * x[k];
        hs[d * N_ATOMS + n] = fmaxf(v, 0.f);
    }
}

// ---------------------------------------------------------------------------
// prep stage: xs += sum_q part; hs = relu(W xs + b)   (16 blocks x 256 atoms)
// ---------------------------------------------------------------------------
__device__ __forceinline__ void prep_stage(
    const int gb, const int tid,
    float* __restrict__ xs, const float* __restrict__ part,
    const float* __restrict__ Wg, const float* __restrict__ bg,
    float* __restrict__ hs)
{
    const int n = gb * 256 + tid;
    float x[DD];
    #pragma unroll
    for (int d = 0; d < DD; ++d) {
        float v = xs[d * N_ATOMS + n];
        #pragma unroll
        for (int q = 0; q < 4; ++q)
            v += part[((size_t)q * DD + d) * N_ATOMS + n];
        x[d] = v;
        xs[d * N_ATOMS + n] = v;
    }
    #pragma unroll
    for (int d = 0; d < DD; ++d) {
        float v = bg[d];
        #pragma unroll
        for (int k = 0; k < DD; ++k) v += Wg[d * DD + k] * x[k];
        hs[d * N_ATOMS + n] = fmaxf(v, 0.f);
    }
}

// ---------------------------------------------------------------------------
// comp stage: final x = xs + sum_q part; block-reduce -> comp_part[16][10]
// ---------------------------------------------------------------------------
__device__ __forceinline__ void comp_stage(
    float* sh, const int tid, const int gb,
    const float* __restrict__ xs, const float* __restrict__ part,
    float* __restrict__ comp_part)
{
    const int wave = tid >> 6, lane = tid & 63;
    const int n = gb * 256 + tid;
    float x[DD];
    #pragma unroll
    for (int d = 0; d < DD; ++d) {
        float v = xs[d * N_ATOMS + n];
        #pragma unroll
        for (int q = 0; q < 4; ++q)
            v += part[((size_t)q * DD + d) * N_ATOMS + n];
        x[d] = v;
    }
    #pragma unroll
    for (int m = 32; m >= 1; m >>= 1) {
        #pragma unroll
        for (int d = 0; d < DD; ++d) x[d] += __shfl_xor(x[d], m, 64);
    }
    if (lane == 0) {
        #pragma unroll
        for (int d = 0; d < DD; ++d) sh[wave * DD + d] = x[d];
    }
    __syncthreads();
    if (tid < DD)
        comp_part[gb * DD + tid] =
            sh[tid] + sh[DD + tid] + sh[2 * DD + tid] + sh[3 * DD + tid];
    __syncthreads();
}

// ---------------------------------------------------------------------------
// hp stage: hp = relu(Wa row + ba) for all words, by the 256 conv blocks
// ---------------------------------------------------------------------------
__device__ __forceinline__ void hp_stage(
    const int bx, const int tid,
    const float* __restrict__ tfin, const float* __restrict__ Wa,
    const float* __restrict__ ba, float* __restrict__ hpb)
{
    const int w_ = bx * 256 + tid;
    float row[DD];
    #pragma unroll
    for (int d = 0; d < DD; ++d) row[d] = tfin[(size_t)w_ * DD + d];
    #pragma unroll
    for (int d = 0; d < DD; ++d) {
        float v = ba[d];
        #pragma unroll
        for (int k = 0; k < DD; ++k) v += Wa[d * DD + k] * row[k];
        hpb[(size_t)w_ * DD + d] = fmaxf(v, 0.f);
    }
}

// ---------------------------------------------------------------------------
// attention stage: 256 blocks x 256 words; per-block partial -> att_part
// ---------------------------------------------------------------------------
__device__ __forceinline__ void attn_stage(
    float* sh, const int tid, const int gb,
    const float* __restrict__ comp_part, const float* __restrict__ Wa,
    const float* __restrict__ ba, const float* __restrict__ hpb,
    float* __restrict__ att_part)
{
    const int wave = tid >> 6, lane = tid & 63;
    if (tid < DD) {
        float c = 0.f;
        #pragma unroll
        for (int p = 0; p < 16; ++p) c += comp_part[p * DD + tid];
        sh[tid] = c * (1.f / N_ATOMS);
    }
    __syncthreads();

    float h[DD];
    #pragma unroll
    for (int d = 0; d < DD; ++d) {
        float v = ba[d];
        #pragma unroll
        for (int k = 0; k < DD; ++k) v += Wa[d * DD + k] * sh[k];
        h[d] = fmaxf(v, 0.f);
    }

    const int w_ = gb * 256 + tid;
    float hp[DD], dotv = 0.f;
    #pragma unroll
    for (int d = 0; d < DD; ++d) {
        hp[d] = hpb[(size_t)w_ * DD + d];
        dotv += h[d] * hp[d];
    }
    const float wgt = tanhf(dotv);

    float y[DD];
    #pragma unroll
    for (int d = 0; d < DD; ++d) y[d] = wgt * hp[d];
    #pragma unroll
    for (int m = 32; m >= 1; m >>= 1) {
        #pragma unroll
        for (int d = 0; d < DD; ++d) y[d] += __shfl_xor(y[d], m, 64);
    }
    __syncthreads();                 // sh[0..10) no longer needed
    if (lane == 0) {
        #pragma unroll
        for (int d = 0; d < DD; ++d) sh[16 + wave * DD + d] = y[d];
    }
    __syncthreads();
    if (tid < DD)
        att_part[gb * DD + tid] =
            sh[16 + tid] + sh[26 + tid] + sh[36 + tid] + sh[46 + tid];
    __syncthreads();
}

// ---------------------------------------------------------------------------
// final stage: reduce att_part (256 rows), build cat[20], 3-layer MLP, out
// ---------------------------------------------------------------------------
__device__ __forceinline__ void final_stage(
    float* sh, const int tid,
    const float* __restrict__ comp_part, const float* __restrict__ att_part,
    const float* __restrict__ Wo, const float* __restrict__ bo,
    const float* __restrict__ Wi, const float* __restrict__ bi,
    float* __restrict__ out)
{
    const int wave = tid >> 6, lane = tid & 63;
    float y[DD];
    #pragma unroll
    for (int d = 0; d < DD; ++d) y[d] = att_part[tid * DD + d];
    #pragma unroll
    for (int m = 32; m >= 1; m >>= 1) {
        #pragma unroll
        for (int d = 0; d < DD; ++d) y[d] += __shfl_xor(y[d], m, 64);
    }
    if (lane == 0) {
        #pragma unroll
        for (int d = 0; d < DD; ++d) sh[wave * DD + d] = y[d];
    }
    __syncthreads();

    float* cat = sh + 64;
    if (tid < DD) {
        float pv = sh[tid] + sh[DD + tid] + sh[2 * DD + tid] + sh[3 * DD + tid];
        cat[DD + tid] = pv * (1.f / L_WORDS);
        float c = 0.f;
        #pragma unroll
        for (int p = 0; p < 16; ++p) c += comp_part[p * DD + tid];
        cat[tid] = c * (1.f / N_ATOMS);
    }
    __syncthreads();
    for (int j = 0; j < 3; ++j) {
        float v = 0.f;
        if (tid < 20) {
            v = bo[j * 20 + tid];
            for (int k = 0; k < 20; ++k) v += Wo[j * 400 + tid * 20 + k] * cat[k];
        }
        __syncthreads();
        if (tid < 20) cat[tid] = fmaxf(v, 0.f);
        __syncthreads();
    }
    if (tid < 2) {
        float v = bi[tid];
        for (int k = 0; k < 20; ++k) v += Wi[tid * 20 + k] * cat[k];
        out[tid] = v;
    }
}

// ---------------------------------------------------------------------------
// The whole pipeline as ONE kernel: 768 co-resident blocks (guaranteed by
// __launch_bounds__(256,3): VGPR<=168, 3x40KB LDS = 120KB/CU, 768 = 256x3),
// 8 hand-rolled device-scope grid barriers replace 8 kernel boundaries.
//  S0 conv-L0          || embed+hs0 (16 gnn blocks)
//  S1 conv-L1          || GNN-L0 (512 blocks)
//  S2 prep1 (16)
//  S3 conv-L2          || GNN-L1
//  S4 prep2 (16)
//  S5 hp precompute    || GNN-L2
//  S6 comp partials (16)
//  S7 attention (256 gnn blocks x 256 words)
//  S8 final reduce + MLP (1 block)
// ---------------------------------------------------------------------------
__global__ __launch_bounds__(256, 3) void mega(
    const int* __restrict__ fp, const float* __restrict__ A,
    const int* __restrict__ words,
    const float* __restrict__ emb_fp, const float* __restrict__ emb_w,
    const float* __restrict__ Wg, const float* __restrict__ bg,
    const float* __restrict__ Wc, const float* __restrict__ bc,
    const float* __restrict__ Wa, const float* __restrict__ ba,
    const float* __restrict__ Wo, const float* __restrict__ bo,
    const float* __restrict__ Wi, const float* __restrict__ bi,
    float* __restrict__ xs, float* __restrict__ hs, float* __restrict__ part,
    float* __restrict__ ta, float* __restrict__ tb, float* __restrict__ hpb,
    float* __restrict__ comp_part, float* __restrict__ att_part,
    unsigned int* __restrict__ bar, float* __restrict__ out)
{
    __shared__ float sh[DD * QCOLS];          // 40 KB (3 blocks/CU = 120 KB)
    const int tid = threadIdx.x;
    const int bx = blockIdx.x;
    const bool is_conv = bx < CONV_BLOCKS;
    const int gb = bx - CONV_BLOCKS;

    // S0
    if (is_conv) conv_stage(sh, tid, bx, nullptr, words, emb_w, Wc, bc, ta);
    else if (gb < 16) embed_stage(gb, tid, fp, emb_fp, Wg, bg, xs, hs);
    gridbar(bar, 0);
    // S1
    if (is_conv) conv_stage(sh, tid, bx, ta, words, emb_w, Wc + 529, bc + 1, tb);
    else gnn_stage(sh, tid, gb, A, hs, part);
    gridbar(bar, 1);
    // S2
    if (!is_conv && gb < 16) prep_stage(gb, tid, xs, part, Wg + 100, bg + 10, hs);
    gridbar(bar, 2);
    // S3
    if (is_conv) conv_stage(sh, tid, bx, tb, words, emb_w, Wc + 1058, bc + 2, ta);
    else gnn_stage(sh, tid, gb, A, hs, part);
    gridbar(bar, 3);
    // S4
    if (!is_conv && gb < 16) prep_stage(gb, tid, xs, part, Wg + 200, bg + 20, hs);
    gridbar(bar, 4);
    // S5
    if (is_conv) hp_stage(bx, tid, ta, Wa, ba, hpb);
    else gnn_stage(sh, tid, gb, A, hs, part);
    gridbar(bar, 5);
    // S6
    if (!is_conv && gb < 16) comp_stage(sh, tid, gb, xs, part, comp_part);
    gridbar(bar, 6);
    // S7
    if (!is_conv && gb < 256) attn_stage(sh, tid, gb, comp_part, Wa, ba, hpb, att_part);
    gridbar(bar, 7);
    // S8
    if (bx == CONV_BLOCKS)
        final_stage(sh, tid, comp_part, att_part, Wo, bo, Wi, bi, out);
}

// ---------------------------------------------------------------------------
extern "C" void kernel_launch(void* const* d_in, const int* in_sizes, int n_in,
                              void* d_out, int out_size, void* d_ws, size_t ws_size,
                              hipStream_t stream)
{
    const int*   fp     = (const int*)d_in[0];
    const float* A      = (const float*)d_in[1];
    const int*   words  = (const int*)d_in[2];
    const float* emb_fp = (const float*)d_in[3];
    const float* emb_w  = (const float*)d_in[4];
    const float* Wg     = (const float*)d_in[5];   // [3][10][10]
    const float* bg     = (const float*)d_in[6];   // [3][10]
    const float* Wc     = (const float*)d_in[7];   // [3][529]
    const float* bc     = (const float*)d_in[8];   // [3]
    const float* Wa     = (const float*)d_in[9];   // [10][10]
    const float* ba     = (const float*)d_in[10];  // [10]
    const float* Wo     = (const float*)d_in[11];  // [3][20][20]
    const float* bo     = (const float*)d_in[12];  // [3][20]
    const float* Wi     = (const float*)d_in[13];  // [2][20]
    const float* bi     = (const float*)d_in[14];  // [2]
    float* out = (float*)d_out;
    float* ws  = (float*)d_ws;

    float* xs        = ws;                   // 40960   SoA [10][4096]
    float* hs        = ws + 40960;           // 40960   SoA (reused per layer)
    float* part      = ws + 81920;           // 163840  SoA [4][10][4096] (reused)
    float* ta        = ws + 245760;          // 655360
    float* tb        = ws + 901120;          // 655360
    float* hpb       = ws + 1556480;         // 655360  hp[65536][10]
    float* comp_part = ws + 2211840;         // 160
    float* att_part  = ws + 2212000;         // 2560
    unsigned int* bar = (unsigned int*)(ws + 2214560);   // 8 barrier slots

    // zero the barrier slots (stream-ordered; ws arrives poisoned each run)
    hipMemsetAsync(bar, 0, 8 * sizeof(unsigned int), stream);

    mega<<<TOTAL_BLOCKS, 256, 0, stream>>>(
        fp, A, words, emb_fp, emb_w, Wg, bg, Wc, bc, Wa, ba, Wo, bo, Wi, bi,
        xs, hs, part, ta, tb, hpb, comp_part, att_part, bar, out);
}

// Round 4
// 212.501 us; speedup vs baseline: 4.2888x; 4.2888x over previous
//
#include <hip/hip_runtime.h>
#include <math.h>

#define N_ATOMS 4096
#define L_WORDS 65536
#define DD 10
#define HALO 11

#define CONV_BLOCKS 256
#define CONV_BLOCK 256
#define RPW 8                     // rows per wave
#define RPB 32                    // rows per block (4 waves)
#define QCOLS 1024                // columns per quarter
#define TOTAL_BLOCKS 768          // 256 conv + 512 gnn = 3 blocks/CU
#define ATT_BLOCKS 64

// ---------------------------------------------------------------------------
// conv stage: one CNN layer over this block's 256 words.
// If hpb != null, also computes hp = relu(Wa·relu(acc)+ba) for its own words
// (hp is pointwise per word, so the conv block that produced the row fuses it).
// ---------------------------------------------------------------------------
__device__ __forceinline__ void conv_stage(
    float* sh, const int tid, const int bx,
    const float* __restrict__ tin, const int* __restrict__ words,
    const float* __restrict__ embed_word, const float* __restrict__ w,
    const float* __restrict__ bptr, float* __restrict__ tout,
    const float* __restrict__ Wa, const float* __restrict__ ba,
    float* __restrict__ hpb)
{
    const int l0 = bx * CONV_BLOCK;
    for (int idx = tid; idx < (CONV_BLOCK + 2 * HALO) * DD; idx += CONV_BLOCK) {
        int rr = idx / DD, d = idx - rr * DD;
        int gr = l0 - HALO + rr;
        float v = 0.f;
        if (gr >= 0 && gr < L_WORDS) {
            if (tin) v = tin[(size_t)gr * DD + d];
            else     v = embed_word[(size_t)words[gr] * DD + d];
        }
        sh[rr * 11 + d] = v;
    }
    __syncthreads();

    const float bias = *bptr;
    float acc[DD];
    #pragma unroll
    for (int d = 0; d < DD; ++d) acc[d] = bias;
    for (int i = 0; i < 23; ++i) {
        float row[DD];
        const float* sr = &sh[(tid + i) * 11];
        #pragma unroll
        for (int c = 0; c < DD; ++c) row[c] = sr[c];
        #pragma unroll
        for (int d = 0; d < DD; ++d) {
            #pragma unroll
            for (int c = 0; c < DD; ++c)
                acc[d] += row[c] * w[i * 23 + (c - d + 11)];
        }
    }
    const int l = l0 + tid;
    if (tout) {
        #pragma unroll
        for (int d = 0; d < DD; ++d)
            tout[(size_t)l * DD + d] = fmaxf(acc[d], 0.f);
    }
    if (hpb) {
        float xsp[DD];
        #pragma unroll
        for (int d = 0; d < DD; ++d) xsp[d] = fmaxf(acc[d], 0.f);
        #pragma unroll
        for (int d = 0; d < DD; ++d) {
            float v = ba[d];
            #pragma unroll
            for (int k = 0; k < DD; ++k) v += Wa[d * DD + k] * xsp[k];
            hpb[(size_t)l * DD + d] = fmaxf(v, 0.f);
        }
    }
}

// ---------------------------------------------------------------------------
// gnn stage with prep folded in: each block builds hs for its own 1024-atom
// quarter (from embeddings in L0, or xs_in + sum_q part_in in L1/L2), then
// computes the A@hs partial. rg==0 blocks persist xs_out for the next layer.
// Redundant per-block prep was measured free (round 0: removing it = ±0.7us).
// ---------------------------------------------------------------------------
__device__ __forceinline__ void gnn_stage(
    float* sh, const int tid, const int b,
    const int* __restrict__ fp, const float* __restrict__ emb_fp,
    const float* __restrict__ xs_in, const float* __restrict__ part_in,
    const float* __restrict__ Wg, const float* __restrict__ bg,
    float* __restrict__ xs_out,
    const float* __restrict__ A, float* __restrict__ part_out)
{
    const int wave = tid >> 6, lane = tid & 63;
    const int q = b & 3, rg = b >> 2;
    const int qbase = q * QCOLS;

    // ---- stage hs for this quarter (in-block prep) ----
    for (int j = 0; j < 4; ++j) {
        const int lc = j * 256 + tid;
        const int n = qbase + lc;
        float x[DD];
        if (xs_in) {
            #pragma unroll
            for (int d = 0; d < DD; ++d) {
                float v = xs_in[d * N_ATOMS + n];
                #pragma unroll
                for (int qq = 0; qq < 4; ++qq)
                    v += part_in[((size_t)qq * DD + d) * N_ATOMS + n];
                x[d] = v;
            }
        } else {
            const float* e = emb_fp + (size_t)fp[n] * DD;
            #pragma unroll
            for (int d = 0; d < DD; ++d) x[d] = e[d];
        }
        if (rg == 0) {
            #pragma unroll
            for (int d = 0; d < DD; ++d) xs_out[d * N_ATOMS + n] = x[d];
        }
        #pragma unroll
        for (int d = 0; d < DD; ++d) {
            float v = bg[d];
            #pragma unroll
            for (int k = 0; k < DD; ++k) v += Wg[d * DD + k] * x[k];
            sh[d * QCOLS + lc] = fmaxf(v, 0.f);
        }
    }
    __syncthreads();

    const int r0 = rg * RPB + wave * RPW;
    const float4* A4 = (const float4*)(A + (size_t)r0 * N_ATOMS) + q * (QCOLS / 4);
    const float4* sh4 = (const float4*)sh;

    float acc[RPW][DD];
    #pragma unroll
    for (int r = 0; r < RPW; ++r)
        #pragma unroll
        for (int d = 0; d < DD; ++d) acc[r][d] = 0.f;

    #pragma unroll 1
    for (int it = 0; it < 4; ++it) {
        const int cb = it * 64 + lane;
        float4 a[RPW];
        #pragma unroll
        for (int r = 0; r < RPW; ++r) a[r] = A4[r * (N_ATOMS / 4) + cb];
        #pragma unroll
        for (int d = 0; d < DD; ++d) {
            float4 h = sh4[d * 256 + cb];
            #pragma unroll
            for (int r = 0; r < RPW; ++r) {
                acc[r][d] += a[r].x * h.x;
                acc[r][d] += a[r].y * h.y;
                acc[r][d] += a[r].z * h.z;
                acc[r][d] += a[r].w * h.w;
            }
        }
    }

    #pragma unroll
    for (int m = 1; m <= 4; m <<= 1) {
        #pragma unroll
        for (int r = 0; r < RPW; ++r)
            #pragma unroll
            for (int d = 0; d < DD; ++d)
                acc[r][d] += __shfl_xor(acc[r][d], m, 64);
    }
    __syncthreads();

    if ((lane & 7) == 0) {
        const int g = lane >> 3;
        float* dst = &sh[(wave * 8 + g) * 80];
        #pragma unroll
        for (int r = 0; r < RPW; ++r)
            #pragma unroll
            for (int d = 0; d < DD; ++d) dst[r * DD + d] = acc[r][d];
    }
    __syncthreads();

    float* pdst = part_out + (size_t)q * DD * N_ATOMS + (size_t)rg * RPB;
    for (int o = tid; o < RPB * DD; o += 256) {
        const int d = o >> 5, rr = o & 31;
        const int w8 = rr >> 3, r = rr & 7;
        float v = 0.f;
        #pragma unroll
        for (int g = 0; g < 8; ++g) v += sh[(w8 * 8 + g) * 80 + r * DD + d];
        pdst[d * N_ATOMS + rr] = v;
    }
}

// ---------------------------------------------------------------------------
// F: one pipeline step. blocks [0,256): conv layer; [256,768): gnn layer.
// ---------------------------------------------------------------------------
__global__ __launch_bounds__(256, 3) void fused_layer(
    const float* __restrict__ A, const int* __restrict__ fp,
    const float* __restrict__ emb_fp,
    const float* __restrict__ xs_in, const float* __restrict__ part_in,
    const float* __restrict__ Wg, const float* __restrict__ bg,
    float* __restrict__ xs_out, float* __restrict__ part_out,
    const float* __restrict__ tin, const int* __restrict__ words,
    const float* __restrict__ emb_w, const float* __restrict__ wc,
    const float* __restrict__ bc, float* __restrict__ tout,
    const float* __restrict__ Wa, const float* __restrict__ ba,
    float* __restrict__ hpb)
{
    __shared__ float sh[DD * QCOLS];     // 40 KB, 3 blocks/CU = 120 KB
    const int tid = threadIdx.x;
    if (blockIdx.x < CONV_BLOCKS)
        conv_stage(sh, tid, blockIdx.x, tin, words, emb_w, wc, bc, tout,
                   Wa, ba, hpb);
    else
        gnn_stage(sh, tid, blockIdx.x - CONV_BLOCKS, fp, emb_fp,
                  xs_in, part_in, Wg, bg, xs_out, A, part_out);
}

// ---------------------------------------------------------------------------
// ATTN+FINAL: 64 blocks x 1024 threads (1 word/thread).
// Each block redundantly reduces comp (L3-resident reads), computes its
// attention partial, publishes it with relaxed agent-scope atomic stores
// (L2-bypass -> no cache-maintenance scans), and a relaxed atomic ticket
// elects the last block to reduce partials + run the final MLP.
// Visibility: each block's atomic stores are vmcnt-drained by __syncthreads()
// before its ticket increment; the last ticket value (63) therefore orders
// after all 63 other blocks' stores. No threadfence anywhere.
// ---------------------------------------------------------------------------
__global__ __launch_bounds__(1024) void attn_final(
    const float* __restrict__ xs2, const float* __restrict__ part2,
    const float* __restrict__ hpb,
    const float* __restrict__ Wa, const float* __restrict__ ba,
    const float* __restrict__ Wo, const float* __restrict__ bo,
    const float* __restrict__ Wi, const float* __restrict__ bi,
    float* att_part, unsigned int* ticket, float* __restrict__ out)
{
    __shared__ float red[16][DD];
    __shared__ float shc[DD];
    __shared__ float cat[20];
    __shared__ int islast;
    const int tid = threadIdx.x, wave = tid >> 6, lane = tid & 63;

    // ---- comp (redundant per block; 800 KB of L3-resident reads) ----
    float c[DD];
    #pragma unroll
    for (int d = 0; d < DD; ++d) c[d] = 0.f;
    #pragma unroll
    for (int s = 0; s < 4; ++s) {
        const int n = s * 1024 + tid;
        #pragma unroll
        for (int d = 0; d < DD; ++d) {
            float v = xs2[d * N_ATOMS + n];
            #pragma unroll
            for (int qq = 0; qq < 4; ++qq)
                v += part2[((size_t)qq * DD + d) * N_ATOMS + n];
            c[d] += v;
        }
    }
    #pragma unroll
    for (int m = 32; m >= 1; m >>= 1) {
        #pragma unroll
        for (int d = 0; d < DD; ++d) c[d] += __shfl_xor(c[d], m, 64);
    }
    if (lane == 0) {
        #pragma unroll
        for (int d = 0; d < DD; ++d) red[wave][d] = c[d];
    }
    __syncthreads();
    if (tid < DD) {
        float v = 0.f;
        #pragma unroll
        for (int w = 0; w < 16; ++w) v += red[w][tid];
        shc[tid] = v * (1.f / N_ATOMS);
    }
    __syncthreads();

    // ---- attention for this thread's word ----
    float h[DD];
    #pragma unroll
    for (int d = 0; d < DD; ++d) {
        float v = ba[d];
        #pragma unroll
        for (int k = 0; k < DD; ++k) v += Wa[d * DD + k] * shc[k];
        h[d] = fmaxf(v, 0.f);
    }
    const int w_ = blockIdx.x * 1024 + tid;
    float hp[DD], dotv = 0.f;
    #pragma unroll
    for (int d = 0; d < DD; ++d) {
        hp[d] = hpb[(size_t)w_ * DD + d];
        dotv += h[d] * hp[d];
    }
    const float wgt = tanhf(dotv);
    float y[DD];
    #pragma unroll
    for (int d = 0; d < DD; ++d) y[d] = wgt * hp[d];
    #pragma unroll
    for (int m = 32; m >= 1; m >>= 1) {
        #pragma unroll
        for (int d = 0; d < DD; ++d) y[d] += __shfl_xor(y[d], m, 64);
    }
    __syncthreads();
    if (lane == 0) {
        #pragma unroll
        for (int d = 0; d < DD; ++d) red[wave][d] = y[d];
    }
    __syncthreads();
    if (tid < DD) {
        float v = 0.f;
        #pragma unroll
        for (int w = 0; w < 16; ++w) v += red[w][tid];
        __hip_atomic_store(att_part + blockIdx.x * DD + tid, v,
                           __ATOMIC_RELAXED, __HIP_MEMORY_SCOPE_AGENT);
    }
    __syncthreads();   // drains each wave's vmcnt -> stores globally visible

    if (tid == 0) {
        unsigned prev = __hip_atomic_fetch_add(ticket, 1u, __ATOMIC_RELAXED,
                                               __HIP_MEMORY_SCOPE_AGENT);
        islast = (prev == ATT_BLOCKS - 1);
    }
    __syncthreads();
    if (!islast) return;
    asm volatile("" ::: "memory");

    // ---- final: reduce 64 partials + MLP (last block only) ----
    float a[DD];
    #pragma unroll
    for (int d = 0; d < DD; ++d) a[d] = 0.f;
    if (tid < ATT_BLOCKS) {
        #pragma unroll
        for (int d = 0; d < DD; ++d)
            a[d] = __hip_atomic_load(att_part + tid * DD + d,
                                     __ATOMIC_RELAXED, __HIP_MEMORY_SCOPE_AGENT);
    }
    if (wave == 0) {
        #pragma unroll
        for (int m = 32; m >= 1; m >>= 1) {
            #pragma unroll
            for (int d = 0; d < DD; ++d) a[d] += __shfl_xor(a[d], m, 64);
        }
    }
    if (tid == 0) {
        #pragma unroll
        for (int d = 0; d < DD; ++d) cat[DD + d] = a[d] * (1.f / L_WORDS);
    }
    if (tid < DD) cat[tid] = shc[tid];   // compound mean already scaled
    __syncthreads();
    for (int j = 0; j < 3; ++j) {
        float v = 0.f;
        if (tid < 20) {
            v = bo[j * 20 + tid];
            for (int k = 0; k < 20; ++k) v += Wo[j * 400 + tid * 20 + k] * cat[k];
        }
        __syncthreads();
        if (tid < 20) cat[tid] = fmaxf(v, 0.f);
        __syncthreads();
    }
    if (tid < 2) {
        float v = bi[tid];
        for (int k = 0; k < 20; ++k) v += Wi[tid * 20 + k] * cat[k];
        out[tid] = v;
    }
}

// ---------------------------------------------------------------------------
extern "C" void kernel_launch(void* const* d_in, const int* in_sizes, int n_in,
                              void* d_out, int out_size, void* d_ws, size_t ws_size,
                              hipStream_t stream)
{
    const int*   fp     = (const int*)d_in[0];
    const float* A      = (const float*)d_in[1];
    const int*   words  = (const int*)d_in[2];
    const float* emb_fp = (const float*)d_in[3];
    const float* emb_w  = (const float*)d_in[4];
    const float* Wg     = (const float*)d_in[5];   // [3][10][10]
    const float* bg     = (const float*)d_in[6];   // [3][10]
    const float* Wc     = (const float*)d_in[7];   // [3][529]
    const float* bc     = (const float*)d_in[8];   // [3]
    const float* Wa     = (const float*)d_in[9];   // [10][10]
    const float* ba     = (const float*)d_in[10];  // [10]
    const float* Wo     = (const float*)d_in[11];  // [3][20][20]
    const float* bo     = (const float*)d_in[12];  // [3][20]
    const float* Wi     = (const float*)d_in[13];  // [2][20]
    const float* bi     = (const float*)d_in[14];  // [2]
    float* out = (float*)d_out;
    float* ws  = (float*)d_ws;

    float* xs0   = ws;                       // 40960   SoA [10][4096]
    float* xs1   = ws + 40960;               // 40960
    float* xs2   = ws + 81920;               // 40960
    float* part0 = ws + 122880;              // 163840  SoA [4][10][4096]
    float* part1 = ws + 286720;              // 163840
    float* part2 = ws + 450560;              // 163840
    float* ta    = ws + 614400;              // 655360
    float* tb    = ws + 1269760;             // 655360
    float* hpb   = ta;                       // alias: ta dead after F1 reads it
    float* att_part = ws + 1925120;          // 640
    unsigned int* ticket = (unsigned int*)(ws + 1925760);

    hipMemsetAsync(ticket, 0, sizeof(unsigned int), stream);

    // F0: conv-L0 || gnn-L0 (embed gathered in-block; rg==0 persists xs0)
    fused_layer<<<TOTAL_BLOCKS, 256, 0, stream>>>(
        A, fp, emb_fp, nullptr, nullptr, Wg, bg, xs0, part0,
        nullptr, words, emb_w, Wc, bc, ta, nullptr, nullptr, nullptr);

    // F1: conv-L1 || gnn-L1 (prep folded in-block)
    fused_layer<<<TOTAL_BLOCKS, 256, 0, stream>>>(
        A, fp, emb_fp, xs0, part0, Wg + 100, bg + 10, xs1, part1,
        ta, words, emb_w, Wc + 529, bc + 1, tb, nullptr, nullptr, nullptr);

    // F2: conv-L2 (+ fused hp) || gnn-L2 (prep folded)
    fused_layer<<<TOTAL_BLOCKS, 256, 0, stream>>>(
        A, fp, emb_fp, xs1, part1, Wg + 200, bg + 20, xs2, part2,
        tb, words, emb_w, Wc + 1058, bc + 2, nullptr, Wa, ba, hpb);

    // ATTN (+ comp in-block, + final MLP in last-arriving block)
    attn_final<<<ATT_BLOCKS, 1024, 0, stream>>>(
        xs2, part2, hpb, Wa, ba, Wo, bo, Wi, bi, att_part, ticket, out);
}

// Round 5
// 203.923 us; speedup vs baseline: 4.4692x; 1.0421x over previous
//
#include <hip/hip_runtime.h>
#include <math.h>

#define N_ATOMS 4096
#define L_WORDS 65536
#define DD 10
#define HALO 11

#define CONV_BLOCKS 256
#define CONV_BLOCK 256
#define RPW 8                     // rows per wave
#define RPB 32                    // rows per block (4 waves)
#define QCOLS 1024                // columns per quarter
#define TOTAL_BLOCKS 768          // 256 conv + 512 gnn = 3 blocks/CU
#define ATT_BLOCKS 64

// ---------------------------------------------------------------------------
// K0: embedding gather -> xs0 planes + hs0 = relu(W0 xs0 + b0) planes.
// Tiny (64 waves): the random emb_fp gather happens ONCE here, not x128
// inside the big kernel (round-4 F0 showed in-block replicated cold gather
// saturates the memory system: 139us, VALUBusy 1.9%).
// ---------------------------------------------------------------------------
__global__ __launch_bounds__(128) void gnn_embed(
    const int* __restrict__ fp, const float* __restrict__ embed_fp,
    const float* __restrict__ Wg, const float* __restrict__ bg,
    float* __restrict__ xs, float* __restrict__ hs)
{
    const int n = blockIdx.x * 128 + threadIdx.x;   // grid 32x128 = 4096
    float x[DD];
    const float* e = embed_fp + (size_t)fp[n] * DD;
    #pragma unroll
    for (int d = 0; d < DD; ++d) x[d] = e[d];
    #pragma unroll
    for (int d = 0; d < DD; ++d) xs[d * N_ATOMS + n] = x[d];
    #pragma unroll
    for (int d = 0; d < DD; ++d) {
        float v = bg[d];
        #pragma unroll
        for (int k = 0; k < DD; ++k) v += Wg[d * DD + k] * x[k];
        hs[d * N_ATOMS + n] = fmaxf(v, 0.f);
    }
}

// ---------------------------------------------------------------------------
// conv stage: one CNN layer over this block's 256 words.
// If hpb != null, also computes hp = relu(Wa·relu(acc)+ba) for its own words
// (hp is pointwise per word, so the conv block that produced the row fuses it).
// ---------------------------------------------------------------------------
__device__ __forceinline__ void conv_stage(
    float* sh, const int tid, const int bx,
    const float* __restrict__ tin, const int* __restrict__ words,
    const float* __restrict__ embed_word, const float* __restrict__ w,
    const float* __restrict__ bptr, float* __restrict__ tout,
    const float* __restrict__ Wa, const float* __restrict__ ba,
    float* __restrict__ hpb)
{
    const int l0 = bx * CONV_BLOCK;
    for (int idx = tid; idx < (CONV_BLOCK + 2 * HALO) * DD; idx += CONV_BLOCK) {
        int rr = idx / DD, d = idx - rr * DD;
        int gr = l0 - HALO + rr;
        float v = 0.f;
        if (gr >= 0 && gr < L_WORDS) {
            if (tin) v = tin[(size_t)gr * DD + d];
            else     v = embed_word[(size_t)words[gr] * DD + d];
        }
        sh[rr * 11 + d] = v;
    }
    __syncthreads();

    const float bias = *bptr;
    float acc[DD];
    #pragma unroll
    for (int d = 0; d < DD; ++d) acc[d] = bias;
    for (int i = 0; i < 23; ++i) {
        float row[DD];
        const float* sr = &sh[(tid + i) * 11];
        #pragma unroll
        for (int c = 0; c < DD; ++c) row[c] = sr[c];
        #pragma unroll
        for (int d = 0; d < DD; ++d) {
            #pragma unroll
            for (int c = 0; c < DD; ++c)
                acc[d] += row[c] * w[i * 23 + (c - d + 11)];
        }
    }
    const int l = l0 + tid;
    if (tout) {
        #pragma unroll
        for (int d = 0; d < DD; ++d)
            tout[(size_t)l * DD + d] = fmaxf(acc[d], 0.f);
    }
    if (hpb) {
        float xsp[DD];
        #pragma unroll
        for (int d = 0; d < DD; ++d) xsp[d] = fmaxf(acc[d], 0.f);
        #pragma unroll
        for (int d = 0; d < DD; ++d) {
            float v = ba[d];
            #pragma unroll
            for (int k = 0; k < DD; ++k) v += Wa[d * DD + k] * xsp[k];
            hpb[(size_t)l * DD + d] = fmaxf(v, 0.f);
        }
    }
}

// ---------------------------------------------------------------------------
// gnn stage: A@hs partial over a 1024-column quarter.
// Staging: if hs_in != null (L0), coalesced plane copy of precomputed hs;
// else (L1/L2) in-block prep x = xs_in + sum_q part_in, hs = relu(Wg x + bg)
// (dense plane reads - measured free in rounds 0/4). rg==0 persists xs_out.
// ---------------------------------------------------------------------------
__device__ __forceinline__ void gnn_stage(
    float* sh, const int tid, const int b,
    const float* __restrict__ hs_in,
    const float* __restrict__ xs_in, const float* __restrict__ part_in,
    const float* __restrict__ Wg, const float* __restrict__ bg,
    float* __restrict__ xs_out,
    const float* __restrict__ A, float* __restrict__ part_out)
{
    const int wave = tid >> 6, lane = tid & 63;
    const int q = b & 3, rg = b >> 2;
    const int qbase = q * QCOLS;

    if (hs_in) {
        // ---- L0: coalesced plane copy of hs quarter ----
        const float4* h4 = (const float4*)hs_in;
        float4* shw = (float4*)sh;
        #pragma unroll
        for (int d = 0; d < DD; ++d)
            shw[d * 256 + tid] = h4[d * (N_ATOMS / 4) + q * 256 + tid];
    } else {
        // ---- L1/L2: in-block prep from xs + parts (dense planes) ----
        for (int j = 0; j < 4; ++j) {
            const int lc = j * 256 + tid;
            const int n = qbase + lc;
            float x[DD];
            #pragma unroll
            for (int d = 0; d < DD; ++d) {
                float v = xs_in[d * N_ATOMS + n];
                #pragma unroll
                for (int qq = 0; qq < 4; ++qq)
                    v += part_in[((size_t)qq * DD + d) * N_ATOMS + n];
                x[d] = v;
            }
            if (rg == 0) {
                #pragma unroll
                for (int d = 0; d < DD; ++d) xs_out[d * N_ATOMS + n] = x[d];
            }
            #pragma unroll
            for (int d = 0; d < DD; ++d) {
                float v = bg[d];
                #pragma unroll
                for (int k = 0; k < DD; ++k) v += Wg[d * DD + k] * x[k];
                sh[d * QCOLS + lc] = fmaxf(v, 0.f);
            }
        }
    }
    __syncthreads();

    const int r0 = rg * RPB + wave * RPW;
    const float4* A4 = (const float4*)(A + (size_t)r0 * N_ATOMS) + q * (QCOLS / 4);
    const float4* sh4 = (const float4*)sh;

    float acc[RPW][DD];
    #pragma unroll
    for (int r = 0; r < RPW; ++r)
        #pragma unroll
        for (int d = 0; d < DD; ++d) acc[r][d] = 0.f;

    #pragma unroll 1
    for (int it = 0; it < 4; ++it) {
        const int cb = it * 64 + lane;
        float4 a[RPW];
        #pragma unroll
        for (int r = 0; r < RPW; ++r) a[r] = A4[r * (N_ATOMS / 4) + cb];
        #pragma unroll
        for (int d = 0; d < DD; ++d) {
            float4 h = sh4[d * 256 + cb];
            #pragma unroll
            for (int r = 0; r < RPW; ++r) {
                acc[r][d] += a[r].x * h.x;
                acc[r][d] += a[r].y * h.y;
                acc[r][d] += a[r].z * h.z;
                acc[r][d] += a[r].w * h.w;
            }
        }
    }

    #pragma unroll
    for (int m = 1; m <= 4; m <<= 1) {
        #pragma unroll
        for (int r = 0; r < RPW; ++r)
            #pragma unroll
            for (int d = 0; d < DD; ++d)
                acc[r][d] += __shfl_xor(acc[r][d], m, 64);
    }
    __syncthreads();

    if ((lane & 7) == 0) {
        const int g = lane >> 3;
        float* dst = &sh[(wave * 8 + g) * 80];
        #pragma unroll
        for (int r = 0; r < RPW; ++r)
            #pragma unroll
            for (int d = 0; d < DD; ++d) dst[r * DD + d] = acc[r][d];
    }
    __syncthreads();

    float* pdst = part_out + (size_t)q * DD * N_ATOMS + (size_t)rg * RPB;
    for (int o = tid; o < RPB * DD; o += 256) {
        const int d = o >> 5, rr = o & 31;
        const int w8 = rr >> 3, r = rr & 7;
        float v = 0.f;
        #pragma unroll
        for (int g = 0; g < 8; ++g) v += sh[(w8 * 8 + g) * 80 + r * DD + d];
        pdst[d * N_ATOMS + rr] = v;
    }
}

// ---------------------------------------------------------------------------
// F: one pipeline step. blocks [0,256): conv layer; [256,768): gnn layer.
// ---------------------------------------------------------------------------
__global__ __launch_bounds__(256, 3) void fused_layer(
    const float* __restrict__ A, const float* __restrict__ hs_in,
    const float* __restrict__ xs_in, const float* __restrict__ part_in,
    const float* __restrict__ Wg, const float* __restrict__ bg,
    float* __restrict__ xs_out, float* __restrict__ part_out,
    const float* __restrict__ tin, const int* __restrict__ words,
    const float* __restrict__ emb_w, const float* __restrict__ wc,
    const float* __restrict__ bc, float* __restrict__ tout,
    const float* __restrict__ Wa, const float* __restrict__ ba,
    float* __restrict__ hpb)
{
    __shared__ float sh[DD * QCOLS];     // 40 KB, 3 blocks/CU = 120 KB
    const int tid = threadIdx.x;
    if (blockIdx.x < CONV_BLOCKS)
        conv_stage(sh, tid, blockIdx.x, tin, words, emb_w, wc, bc, tout,
                   Wa, ba, hpb);
    else
        gnn_stage(sh, tid, blockIdx.x - CONV_BLOCKS, hs_in,
                  xs_in, part_in, Wg, bg, xs_out, A, part_out);
}

// ---------------------------------------------------------------------------
// ATTN+FINAL: 64 blocks x 1024 threads (1 word/thread).
// Each block redundantly reduces comp (L3-resident reads), computes its
// attention partial, publishes it with relaxed agent-scope atomic stores
// (L2-bypass -> no cache-maintenance scans), and a relaxed atomic ticket
// elects the last block to reduce partials + run the final MLP.
// ---------------------------------------------------------------------------
__global__ __launch_bounds__(1024) void attn_final(
    const float* __restrict__ xs2, const float* __restrict__ part2,
    const float* __restrict__ hpb,
    const float* __restrict__ Wa, const float* __restrict__ ba,
    const float* __restrict__ Wo, const float* __restrict__ bo,
    const float* __restrict__ Wi, const float* __restrict__ bi,
    float* att_part, unsigned int* ticket, float* __restrict__ out)
{
    __shared__ float red[16][DD];
    __shared__ float shc[DD];
    __shared__ float cat[20];
    __shared__ int islast;
    const int tid = threadIdx.x, wave = tid >> 6, lane = tid & 63;

    // ---- comp (redundant per block; 800 KB of L3-resident reads) ----
    float c[DD];
    #pragma unroll
    for (int d = 0; d < DD; ++d) c[d] = 0.f;
    #pragma unroll
    for (int s = 0; s < 4; ++s) {
        const int n = s * 1024 + tid;
        #pragma unroll
        for (int d = 0; d < DD; ++d) {
            float v = xs2[d * N_ATOMS + n];
            #pragma unroll
            for (int qq = 0; qq < 4; ++qq)
                v += part2[((size_t)qq * DD + d) * N_ATOMS + n];
            c[d] += v;
        }
    }
    #pragma unroll
    for (int m = 32; m >= 1; m >>= 1) {
        #pragma unroll
        for (int d = 0; d < DD; ++d) c[d] += __shfl_xor(c[d], m, 64);
    }
    if (lane == 0) {
        #pragma unroll
        for (int d = 0; d < DD; ++d) red[wave][d] = c[d];
    }
    __syncthreads();
    if (tid < DD) {
        float v = 0.f;
        #pragma unroll
        for (int w = 0; w < 16; ++w) v += red[w][tid];
        shc[tid] = v * (1.f / N_ATOMS);
    }
    __syncthreads();

    // ---- attention for this thread's word ----
    float h[DD];
    #pragma unroll
    for (int d = 0; d < DD; ++d) {
        float v = ba[d];
        #pragma unroll
        for (int k = 0; k < DD; ++k) v += Wa[d * DD + k] * shc[k];
        h[d] = fmaxf(v, 0.f);
    }
    const int w_ = blockIdx.x * 1024 + tid;
    float hp[DD], dotv = 0.f;
    #pragma unroll
    for (int d = 0; d < DD; ++d) {
        hp[d] = hpb[(size_t)w_ * DD + d];
        dotv += h[d] * hp[d];
    }
    const float wgt = tanhf(dotv);
    float y[DD];
    #pragma unroll
    for (int d = 0; d < DD; ++d) y[d] = wgt * hp[d];
    #pragma unroll
    for (int m = 32; m >= 1; m >>= 1) {
        #pragma unroll
        for (int d = 0; d < DD; ++d) y[d] += __shfl_xor(y[d], m, 64);
    }
    __syncthreads();
    if (lane == 0) {
        #pragma unroll
        for (int d = 0; d < DD; ++d) red[wave][d] = y[d];
    }
    __syncthreads();
    if (tid < DD) {
        float v = 0.f;
        #pragma unroll
        for (int w = 0; w < 16; ++w) v += red[w][tid];
        __hip_atomic_store(att_part + blockIdx.x * DD + tid, v,
                           __ATOMIC_RELAXED, __HIP_MEMORY_SCOPE_AGENT);
    }
    __syncthreads();   // drains each wave's vmcnt -> stores globally visible

    if (tid == 0) {
        unsigned prev = __hip_atomic_fetch_add(ticket, 1u, __ATOMIC_RELAXED,
                                               __HIP_MEMORY_SCOPE_AGENT);
        islast = (prev == ATT_BLOCKS - 1);
    }
    __syncthreads();
    if (!islast) return;
    asm volatile("" ::: "memory");

    // ---- final: reduce 64 partials + MLP (last block only) ----
    float a[DD];
    #pragma unroll
    for (int d = 0; d < DD; ++d) a[d] = 0.f;
    if (tid < ATT_BLOCKS) {
        #pragma unroll
        for (int d = 0; d < DD; ++d)
            a[d] = __hip_atomic_load(att_part + tid * DD + d,
                                     __ATOMIC_RELAXED, __HIP_MEMORY_SCOPE_AGENT);
    }
    if (wave == 0) {
        #pragma unroll
        for (int m = 32; m >= 1; m >>= 1) {
            #pragma unroll
            for (int d = 0; d < DD; ++d) a[d] += __shfl_xor(a[d], m, 64);
        }
    }
    if (tid == 0) {
        #pragma unroll
        for (int d = 0; d < DD; ++d) cat[DD + d] = a[d] * (1.f / L_WORDS);
    }
    if (tid < DD) cat[tid] = shc[tid];   // compound mean already scaled
    __syncthreads();
    for (int j = 0; j < 3; ++j) {
        float v = 0.f;
        if (tid < 20) {
            v = bo[j * 20 + tid];
            for (int k = 0; k < 20; ++k) v += Wo[j * 400 + tid * 20 + k] * cat[k];
        }
        __syncthreads();
        if (tid < 20) cat[tid] = fmaxf(v, 0.f);
        __syncthreads();
    }
    if (tid < 2) {
        float v = bi[tid];
        for (int k = 0; k < 20; ++k) v += Wi[tid * 20 + k] * cat[k];
        out[tid] = v;
    }
}

// ---------------------------------------------------------------------------
extern "C" void kernel_launch(void* const* d_in, const int* in_sizes, int n_in,
                              void* d_out, int out_size, void* d_ws, size_t ws_size,
                              hipStream_t stream)
{
    const int*   fp     = (const int*)d_in[0];
    const float* A      = (const float*)d_in[1];
    const int*   words  = (const int*)d_in[2];
    const float* emb_fp = (const float*)d_in[3];
    const float* emb_w  = (const float*)d_in[4];
    const float* Wg     = (const float*)d_in[5];   // [3][10][10]
    const float* bg     = (const float*)d_in[6];   // [3][10]
    const float* Wc     = (const float*)d_in[7];   // [3][529]
    const float* bc     = (const float*)d_in[8];   // [3]
    const float* Wa     = (const float*)d_in[9];   // [10][10]
    const float* ba     = (const float*)d_in[10];  // [10]
    const float* Wo     = (const float*)d_in[11];  // [3][20][20]
    const float* bo     = (const float*)d_in[12];  // [3][20]
    const float* Wi     = (const float*)d_in[13];  // [2][20]
    const float* bi     = (const float*)d_in[14];  // [2]
    float* out = (float*)d_out;
    float* ws  = (float*)d_ws;

    float* xs0   = ws;                       // 40960   SoA [10][4096]
    float* xs1   = ws + 40960;               // 40960
    float* xs2   = ws + 81920;               // 40960
    float* hs0   = ws + 122880;              // 40960   SoA planes (L0 only)
    float* part0 = ws + 163840;              // 163840  SoA [4][10][4096]
    float* part1 = ws + 327680;              // 163840
    float* part2 = ws + 491520;              // 163840
    float* ta    = ws + 655360;              // 655360
    float* tb    = ws + 1310720;             // 655360
    float* hpb   = ta;                       // alias: ta dead after F1 reads it
    float* att_part = ws + 1966080;          // 640
    unsigned int* ticket = (unsigned int*)(ws + 1966720);

    hipMemsetAsync(ticket, 0, sizeof(unsigned int), stream);

    // K0: embed gather once (tiny) -> xs0 + hs0 planes
    gnn_embed<<<N_ATOMS / 128, 128, 0, stream>>>(fp, emb_fp, Wg, bg, xs0, hs0);

    // F0: conv-L0 || gnn-L0 (stage = coalesced hs0 plane copy)
    fused_layer<<<TOTAL_BLOCKS, 256, 0, stream>>>(
        A, hs0, nullptr, nullptr, Wg, bg, nullptr, part0,
        nullptr, words, emb_w, Wc, bc, ta, nullptr, nullptr, nullptr);

    // F1: conv-L1 || gnn-L1 (prep folded in-block)
    fused_layer<<<TOTAL_BLOCKS, 256, 0, stream>>>(
        A, nullptr, xs0, part0, Wg + 100, bg + 10, xs1, part1,
        ta, words, emb_w, Wc + 529, bc + 1, tb, nullptr, nullptr, nullptr);

    // F2: conv-L2 (+ fused hp) || gnn-L2 (prep folded)
    fused_layer<<<TOTAL_BLOCKS, 256, 0, stream>>>(
        A, nullptr, xs1, part1, Wg + 200, bg + 20, xs2, part2,
        tb, words, emb_w, Wc + 1058, bc + 2, nullptr, Wa, ba, hpb);

    // ATTN (+ comp in-block, + final MLP in last-arriving block)
    attn_final<<<ATT_BLOCKS, 1024, 0, stream>>>(
        xs2, part2, hpb, Wa, ba, Wo, bo, Wi, bi, att_part, ticket, out);
}